// Round 1
// baseline (224.671 us; speedup 1.0000x reference)
//
#include <hip/hip_runtime.h>

#define D     512
#define HW    (D * D)
#define BLOCK 256
// 8 pixels per thread -> 2048 px per block -> 4 rows per block, 128 blocks per image

// General path: full reference bilinear with per-lane gathers (ind = y + D*x).
__device__ __forceinline__ void samp_gather(const float* __restrict__ im,
    float rx, float ry, float m, float r3[3], float* oob)
{
    float cxq = fminf(fmaxf(rx, 0.001f), 510.999f);
    float cyq = fminf(fmaxf(ry, 0.001f), 510.999f);
    float dx = rx - cxq, dy = ry - cyq;
    *oob += dx * dx + dy * dy;
    float xff = floorf(cxq), xcf = ceilf(cxq);
    float yff = floorf(cyq), ycf = ceilf(cyq);
    float wxf = 1.0f - (cxq - xff), wxc = 1.0f - (xcf - cxq);
    float wyf = 1.0f - (cyq - yff), wyc = 1.0f - (ycf - cyq);
    float w00 = wxf * wyf, w10 = wxc * wyf, w01 = wxf * wyc, w11 = wxc * wyc;
    int xf = (int)xff, xc = (int)xcf, yf = (int)yff, yc = (int)ycf;
    int i00 = yf + D * xf, i10 = yf + D * xc;
    int i01 = yc + D * xf, i11 = yc + D * xc;
#pragma unroll
    for (int c = 0; c < 3; ++c) {
        const float* __restrict__ ch = im + (size_t)c * HW;
        r3[c] += m * (w00 * ch[i00] + w10 * ch[i10] + w01 * ch[i01] + w11 * ch[i11]);
    }
}

__global__ void __launch_bounds__(BLOCK) vm_kernel(
    const float* __restrict__ im1, const float* __restrict__ im2,
    const float* __restrict__ C,   const float* __restrict__ M1,
    const float* __restrict__ M2,  float* __restrict__ out,
    double* __restrict__ partials)
{
    int b  = blockIdx.x;
    int n  = b >> 7;                 // 128 blocks per image
    int rb = b & 127;                // 4 rows per block
    int t  = threadIdx.x;
    int i  = (rb << 2) + (t >> 6);   // one row per wave
    int jA = (t & 63) << 2;          // group A: cols jA..jA+3; group B: +256

    const float* base1 = im1 + (size_t)n * 3 * HW;
    const float* base2 = im2 + (size_t)n * 3 * HW;

    // When a sample fully clips high, clipped coord == 510.999f (constant) so
    // bilinear weights are constants and the sample value is block-uniform:
    //   S = WF*WF*p(510,510) + WC*WF*p(x=511,y=510) + WF*WC*p(510,511) + WC*WC*p(511,511)
    // (exact f32 replication of reference weight arithmetic)
    const float WF = 1.0f - (510.999f - 510.0f);   // x/y-floor weight
    const float WC = 1.0f - (511.0f - 510.999f);   // x/y-ceil  weight
    float S1[3], S2[3];
#pragma unroll
    for (int c = 0; c < 3; ++c) {
        const float* c1 = base1 + (size_t)c * HW;
        const float* c2 = base2 + (size_t)c * HW;
        S1[c] = (WF * WF) * c1[510 + D * 510] + (WC * WF) * c1[510 + D * 511]
              + (WF * WC) * c1[511 + D * 510] + (WC * WC) * c1[511 + D * 511];
        S2[c] = (WF * WF) * c2[510 + D * 510] + (WC * WF) * c2[510 + D * 511]
              + (WF * WC) * c2[511 + D * 510] + (WC * WC) * c2[511 + D * 511];
    }

    size_t cb = (size_t)n * 2 * HW, mb = (size_t)n * HW, ob = (size_t)n * 3 * HW;
    size_t ppA = (size_t)i * D + jA;
    size_t ppB = ppA + 256;

    // Issue all 8 input loads up front (128 B in flight per thread).
    float4 cxA = *(const float4*)(C  + cb + ppA);
    float4 cxB = *(const float4*)(C  + cb + ppB);
    float4 cyA = *(const float4*)(C  + cb + HW + ppA);
    float4 cyB = *(const float4*)(C  + cb + HW + ppB);
    float4 m1A = *(const float4*)(M1 + mb + ppA);
    float4 m1B = *(const float4*)(M1 + mb + ppB);
    float4 m2A = *(const float4*)(M2 + mb + ppA);
    float4 m2B = *(const float4*)(M2 + mb + ppB);

    float cxv[8] = {cxA.x, cxA.y, cxA.z, cxA.w, cxB.x, cxB.y, cxB.z, cxB.w};
    float cyv[8] = {cyA.x, cyA.y, cyA.z, cyA.w, cyB.x, cyB.y, cyB.z, cyB.w};
    float m1v[8] = {m1A.x, m1A.y, m1A.z, m1A.w, m1B.x, m1B.y, m1B.z, m1B.w};
    float m2v[8] = {m2A.x, m2A.y, m2A.z, m2A.w, m2B.x, m2B.y, m2B.z, m2B.w};

    float fi = (float)i;
    float o0[8], o1[8], o2[8];
    float oob = 0.0f;

#pragma unroll
    for (int k = 0; k < 8; ++k) {
        int j = jA + (k < 4 ? k : 252 + k);   // k>=4 -> group B at +256
        float fj  = (float)j;
        float cx  = cxv[k], cy = cyv[k];
        float m1s = m1v[k], m2s = m2v[k];

        float tot = m1s + m2s;
        float inv = 1.0f / tot;
        float m1n = m1s * inv, m2n = m2s * inv;

        float rx1 = (fi + cx) * 512.0f, ry1 = (fj + cy) * 512.0f;
        float rx2 = (fi - cx) * 512.0f, ry2 = (fj - cy) * 512.0f;

        // exact: (fi - |cx|)*512 == min(rx1, rx2) (f32 sub + pow2 mul are exact)
        bool fast = ((fi - fabsf(cx)) * 512.0f >= 510.999f)
                 && ((fj - fabsf(cy)) * 512.0f >= 510.999f);

        float r3[3];
        if (fast) {
            float dx1 = rx1 - 510.999f, dy1 = ry1 - 510.999f;
            float dx2 = rx2 - 510.999f, dy2 = ry2 - 510.999f;
            oob += dx1 * dx1 + dy1 * dy1 + dx2 * dx2 + dy2 * dy2;
            r3[0] = m1n * S1[0] + m2n * S2[0];
            r3[1] = m1n * S1[1] + m2n * S2[1];
            r3[2] = m1n * S1[2] + m2n * S2[2];
        } else {
            r3[0] = r3[1] = r3[2] = 0.0f;
            samp_gather(base1, rx1, ry1, m1n, r3, &oob);
            samp_gather(base2, rx2, ry2, m2n, r3, &oob);
        }
        o0[k] = r3[0]; o1[k] = r3[1]; o2[k] = r3[2];
    }

    *(float4*)(out + ob + ppA)              = make_float4(o0[0], o0[1], o0[2], o0[3]);
    *(float4*)(out + ob + ppB)              = make_float4(o0[4], o0[5], o0[6], o0[7]);
    *(float4*)(out + ob + HW + ppA)         = make_float4(o1[0], o1[1], o1[2], o1[3]);
    *(float4*)(out + ob + HW + ppB)         = make_float4(o1[4], o1[5], o1[6], o1[7]);
    *(float4*)(out + ob + 2 * HW + ppA)     = make_float4(o2[0], o2[1], o2[2], o2[3]);
    *(float4*)(out + ob + 2 * HW + ppB)     = make_float4(o2[4], o2[5], o2[6], o2[7]);

    // ---- block reduction of oob (f32 in-wave, f64 across waves) ----
    for (int off = 32; off > 0; off >>= 1)
        oob += __shfl_down(oob, off, 64);

    __shared__ float soob[BLOCK / 64];
    int lane = threadIdx.x & 63;
    int w    = threadIdx.x >> 6;
    if (lane == 0) soob[w] = oob;
    __syncthreads();
    if (threadIdx.x == 0)
        partials[blockIdx.x] = (double)soob[0] + (double)soob[1]
                             + (double)soob[2] + (double)soob[3];
}

__global__ void __launch_bounds__(BLOCK) reduce_kernel(
    const double* __restrict__ partials, int nparts,
    float* __restrict__ out_last, double scale)
{
    double s = 0.0;
    for (int i = threadIdx.x; i < nparts; i += BLOCK)
        s += partials[i];
    for (int off = 32; off > 0; off >>= 1)
        s += __shfl_down(s, off, 64);

    __shared__ double sm[BLOCK / 64];
    int lane = threadIdx.x & 63;
    int w    = threadIdx.x >> 6;
    if (lane == 0) sm[w] = s;
    __syncthreads();
    if (threadIdx.x == 0)
        *out_last = (float)((sm[0] + sm[1] + sm[2] + sm[3]) * scale);
}

extern "C" void kernel_launch(void* const* d_in, const int* in_sizes, int n_in,
                              void* d_out, int out_size, void* d_ws, size_t ws_size,
                              hipStream_t stream) {
    const float* im1 = (const float*)d_in[0];
    const float* im2 = (const float*)d_in[1];
    const float* C   = (const float*)d_in[2];
    const float* M1  = (const float*)d_in[3];
    const float* M2  = (const float*)d_in[4];
    float* out = (float*)d_out;
    double* ws = (double*)d_ws;

    int N = in_sizes[3] / HW;        // M1 is [N,1,H,W]
    int blocks = N * 128;            // 2048 px per block -> 2048 blocks

    vm_kernel<<<blocks, BLOCK, 0, stream>>>(im1, im2, C, M1, M2, out, ws);

    // loss = sum / (N*2*HW) / D^2 * 1e-4  (a and b share the mean count)
    double scale = 1.0 / ((double)N * 2.0 * (double)HW) / (double)HW * 1e-4;
    reduce_kernel<<<1, BLOCK, 0, stream>>>(ws, blocks, out + (out_size - 1), scale);
}

// Round 2
// 205.254 us; speedup vs baseline: 1.0946x; 1.0946x over previous
//
#include <hip/hip_runtime.h>

#define D     512
#define HW    (D * D)
#define BLOCK 256
// Round-0 row geometry (2 px/thread, j0 = 2t: slow cols j<8 confined to wave 0),
// but each block handles 4 rows of ONE image at stride 128 (i = ib + {0,128,256,384})
// -> 2048 blocks, prologue amortized 4x, slow edge rows spread 1-per-block.

// General path: full reference bilinear with per-lane gathers (ind = y + D*x).
__device__ __forceinline__ void samp_gather(const float* __restrict__ im,
    float rx, float ry, float m, float r3[3], float* oob)
{
    float cxq = fminf(fmaxf(rx, 0.001f), 510.999f);
    float cyq = fminf(fmaxf(ry, 0.001f), 510.999f);
    float dx = rx - cxq, dy = ry - cyq;
    *oob += dx * dx + dy * dy;
    float xff = floorf(cxq), xcf = ceilf(cxq);
    float yff = floorf(cyq), ycf = ceilf(cyq);
    float wxf = 1.0f - (cxq - xff), wxc = 1.0f - (xcf - cxq);
    float wyf = 1.0f - (cyq - yff), wyc = 1.0f - (ycf - cyq);
    float w00 = wxf * wyf, w10 = wxc * wyf, w01 = wxf * wyc, w11 = wxc * wyc;
    int xf = (int)xff, xc = (int)xcf, yf = (int)yff, yc = (int)ycf;
    int i00 = yf + D * xf, i10 = yf + D * xc;
    int i01 = yc + D * xf, i11 = yc + D * xc;
#pragma unroll
    for (int c = 0; c < 3; ++c) {
        const float* __restrict__ ch = im + (size_t)c * HW;
        r3[c] += m * (w00 * ch[i00] + w10 * ch[i10] + w01 * ch[i01] + w11 * ch[i11]);
    }
}

__global__ void __launch_bounds__(BLOCK) vm_kernel(
    const float* __restrict__ im1, const float* __restrict__ im2,
    const float* __restrict__ C,   const float* __restrict__ M1,
    const float* __restrict__ M2,  float* __restrict__ out,
    double* __restrict__ partials)
{
    int b  = blockIdx.x;
    int n  = b >> 7;                 // 128 blocks per image
    int ib = b & 127;                // rows ib, ib+128, ib+256, ib+384
    int t  = threadIdx.x;
    int j0 = t * 2;                  // wave w covers cols [128w, 128w+128)

    const float* base1 = im1 + (size_t)n * 3 * HW;
    const float* base2 = im2 + (size_t)n * 3 * HW;

    // When a sample fully clips high, clipped coord == 510.999f (constant) so
    // bilinear weights are constants and the sample value is block-uniform:
    //   S = WF*WF*p(510,510) + WC*WF*p(x=511,y=510) + WF*WC*p(510,511) + WC*WC*p(511,511)
    // (exact f32 replication of reference weight arithmetic)
    const float WF = 1.0f - (510.999f - 510.0f);   // x/y-floor weight
    const float WC = 1.0f - (511.0f - 510.999f);   // x/y-ceil  weight
    float S1[3], S2[3];
#pragma unroll
    for (int c = 0; c < 3; ++c) {
        const float* c1 = base1 + (size_t)c * HW;
        const float* c2 = base2 + (size_t)c * HW;
        S1[c] = (WF * WF) * c1[510 + D * 510] + (WC * WF) * c1[510 + D * 511]
              + (WF * WC) * c1[511 + D * 510] + (WC * WC) * c1[511 + D * 511];
        S2[c] = (WF * WF) * c2[510 + D * 510] + (WC * WF) * c2[510 + D * 511]
              + (WF * WC) * c2[511 + D * 510] + (WC * WC) * c2[511 + D * 511];
    }

    size_t cb = (size_t)n * 2 * HW, mb = (size_t)n * HW, ob = (size_t)n * 3 * HW;
    float oob = 0.0f;

#pragma unroll
    for (int r = 0; r < 4; ++r) {
        int i = ib + (r << 7);
        size_t pp = (size_t)i * D + j0;

        float2 cx2 = *(const float2*)(C  + cb + pp);
        float2 cy2 = *(const float2*)(C  + cb + HW + pp);
        float2 m12 = *(const float2*)(M1 + mb + pp);
        float2 m22 = *(const float2*)(M2 + mb + pp);

        float fi = (float)i;
        float o0[2], o1[2], o2[2];

#pragma unroll
        for (int k = 0; k < 2; ++k) {
            float cx  = k ? cx2.y : cx2.x;
            float cy  = k ? cy2.y : cy2.x;
            float m1v = k ? m12.y : m12.x;
            float m2v = k ? m22.y : m22.x;
            float fj  = (float)(j0 + k);

            float tot = m1v + m2v;
            float inv = 1.0f / tot;
            float m1n = m1v * inv, m2n = m2v * inv;

            float rx1 = (fi + cx) * 512.0f, ry1 = (fj + cy) * 512.0f;
            float rx2 = (fi - cx) * 512.0f, ry2 = (fj - cy) * 512.0f;

            // exact: (fi - |cx|)*512 == min(rx1, rx2) (f32 sub + pow2 mul are exact)
            bool fast = ((fi - fabsf(cx)) * 512.0f >= 510.999f)
                     && ((fj - fabsf(cy)) * 512.0f >= 510.999f);

            float r3[3];
            if (fast) {
                float dx1 = rx1 - 510.999f, dy1 = ry1 - 510.999f;
                float dx2 = rx2 - 510.999f, dy2 = ry2 - 510.999f;
                oob += dx1 * dx1 + dy1 * dy1 + dx2 * dx2 + dy2 * dy2;
                r3[0] = m1n * S1[0] + m2n * S2[0];
                r3[1] = m1n * S1[1] + m2n * S2[1];
                r3[2] = m1n * S1[2] + m2n * S2[2];
            } else {
                r3[0] = r3[1] = r3[2] = 0.0f;
                samp_gather(base1, rx1, ry1, m1n, r3, &oob);
                samp_gather(base2, rx2, ry2, m2n, r3, &oob);
            }
            o0[k] = r3[0]; o1[k] = r3[1]; o2[k] = r3[2];
        }

        *(float2*)(out + ob + pp)          = make_float2(o0[0], o0[1]);
        *(float2*)(out + ob + HW + pp)     = make_float2(o1[0], o1[1]);
        *(float2*)(out + ob + 2 * HW + pp) = make_float2(o2[0], o2[1]);
    }

    // ---- block reduction of oob (f32 in-wave, f64 across waves) ----
    for (int off = 32; off > 0; off >>= 1)
        oob += __shfl_down(oob, off, 64);

    __shared__ float soob[BLOCK / 64];
    int lane = threadIdx.x & 63;
    int w    = threadIdx.x >> 6;
    if (lane == 0) soob[w] = oob;
    __syncthreads();
    if (threadIdx.x == 0)
        partials[blockIdx.x] = (double)soob[0] + (double)soob[1]
                             + (double)soob[2] + (double)soob[3];
}

__global__ void __launch_bounds__(BLOCK) reduce_kernel(
    const double* __restrict__ partials, int nparts,
    float* __restrict__ out_last, double scale)
{
    double s = 0.0;
    for (int i = threadIdx.x; i < nparts; i += BLOCK)
        s += partials[i];
    for (int off = 32; off > 0; off >>= 1)
        s += __shfl_down(s, off, 64);

    __shared__ double sm[BLOCK / 64];
    int lane = threadIdx.x & 63;
    int w    = threadIdx.x >> 6;
    if (lane == 0) sm[w] = s;
    __syncthreads();
    if (threadIdx.x == 0)
        *out_last = (float)((sm[0] + sm[1] + sm[2] + sm[3]) * scale);
}

extern "C" void kernel_launch(void* const* d_in, const int* in_sizes, int n_in,
                              void* d_out, int out_size, void* d_ws, size_t ws_size,
                              hipStream_t stream) {
    const float* im1 = (const float*)d_in[0];
    const float* im2 = (const float*)d_in[1];
    const float* C   = (const float*)d_in[2];
    const float* M1  = (const float*)d_in[3];
    const float* M2  = (const float*)d_in[4];
    float* out = (float*)d_out;
    double* ws = (double*)d_ws;

    int N = in_sizes[3] / HW;        // M1 is [N,1,H,W]
    int blocks = N * 128;            // 4 rows per block -> 2048 blocks

    vm_kernel<<<blocks, BLOCK, 0, stream>>>(im1, im2, C, M1, M2, out, ws);

    // loss = sum / (N*2*HW) / D^2 * 1e-4  (a and b share the mean count)
    double scale = 1.0 / ((double)N * 2.0 * (double)HW) / (double)HW * 1e-4;
    reduce_kernel<<<1, BLOCK, 0, stream>>>(ws, blocks, out + (out_size - 1), scale);
}